// Round 12
// baseline (17464.546 us; speedup 1.0000x reference)
//
#include <hip/hip_runtime.h>
#include <hip/hip_bf16.h>

// HMM backward recursion, B=32, T=256, H=1024, V=50257.
// Double-step fusion: 16 persistent WGs exchange a normalized state vector V
// every TWO steps. Each dstep, every WG redundantly computes the full
// intermediate step (A is row-stochastic in exp domain -> A.V is a convex
// combination, no magnitude growth; drift only from Ee=exp(beta) factors),
// takes the EXACT max M1 (identical across WGs, deterministic), stores the
// raw intermediate in LDS, computes its 64-slice of the second step, and
// publishes P2/M1 with G += log(M1). No wrec exchange, no exp/log inner loop.
// Exchange primitives = round-7 proven (64 per-wave flags, sc0sc1, vm0+flag).

#define Hdim 1024
#define Bdim 32
#define Tdim 256
#define Vdim 50257
#define NWG  16
#define NDSTEP 127

typedef __attribute__((ext_vector_type(8))) __bf16 bf16x8;
typedef __attribute__((ext_vector_type(4))) float  f32x4;
typedef __attribute__((ext_vector_type(4))) unsigned u32x4;

// workspace layout (bytes)
#define OFF_ABF   0                          // exp(alpha) bf16: 2 MB
#define OFF_YBUF  2097152                    // [2][16][4096B] = 131072
#define OFF_PSUM  (OFF_YBUF + 131072)        // 32 f32 (pad 128)
#define OFF_RBUF  (OFF_PSUM + 128)           // 32 f32 (pad 128)
#define OFF_FLG   (OFF_RBUF + 128)           // [2][64] x 64B = 8192
#define OFF_END0  (OFF_FLG + 8192)
#define OFF_E     (((OFF_END0) + 4095) & ~4095)
#define WS_E_NEED ((size_t)OFF_E + (size_t)Tdim * Bdim * Hdim * 4)

// LDS carve: Vm = 32 rows x 2048B (bf16, XOR-swizzled) + Ltile + Msh
#define SM_LTILE   65536
#define SM_MSH     (65536 + 512)
#define SMEM_BYTES (65536 + 512 + 256)

#define WAITCNT_VM(n) do { \
    asm volatile("s_waitcnt vmcnt(" #n ")" ::: "memory"); \
    __builtin_amdgcn_sched_barrier(0); } while (0)

// ---- sc0 sc1 (device-scope, cache-bypass) exchange helpers (round-7) ----
__device__ __forceinline__ void st_b16_sc(void* p, unsigned v) {
    asm volatile("global_store_short %0, %1, off sc0 sc1" :: "v"(p), "v"(v) : "memory");
}
__device__ __forceinline__ void st_b32_sc(void* p, unsigned v) {
    asm volatile("global_store_dword %0, %1, off sc0 sc1" :: "v"(p), "v"(v) : "memory");
}
__device__ __forceinline__ u32x4 ld_b128_sc(const void* p) {
    u32x4 r;
    asm volatile("global_load_dwordx4 %0, %1, off sc0 sc1" : "=v"(r) : "v"(p) : "memory");
    return r;
}
__device__ __forceinline__ unsigned ld_u32sync_sc(const void* p) {
    unsigned r;
    asm volatile("global_load_dword %0, %1, off sc0 sc1\n\ts_waitcnt vmcnt(0)"
                 : "=v"(r) : "v"(p) : "memory");
    return r;
}

__global__ void k_expA(const float* __restrict__ alpha, __bf16* __restrict__ Abf) {
    int idx = (blockIdx.x * 256 + threadIdx.x) * 4;
    float4 v = *(const float4*)(alpha + idx);
    union { __bf16 h[4]; uint2 u; } cv;
    cv.h[0] = (__bf16)__expf(v.x);
    cv.h[1] = (__bf16)__expf(v.y);
    cv.h[2] = (__bf16)__expf(v.z);
    cv.h[3] = (__bf16)__expf(v.w);
    *(uint2*)(Abf + idx) = cv.u;
}

// E[t][b][i] = exp(beta[i, x[b,t]])
__global__ void k_gather(const int* __restrict__ x, const float* __restrict__ beta,
                         float* __restrict__ E) {
    int tb = blockIdx.x;            // t*32 + b
    int t  = tb >> 5, b = tb & 31;
    int xv = x[b * Tdim + t];
    int i  = threadIdx.x * 4;
    float4 v;
    v.x = __expf(beta[(size_t)(i + 0) * Vdim + xv]);
    v.y = __expf(beta[(size_t)(i + 1) * Vdim + xv]);
    v.z = __expf(beta[(size_t)(i + 2) * Vdim + xv]);
    v.w = __expf(beta[(size_t)(i + 3) * Vdim + xv]);
    *(float4*)(E + ((size_t)t * Bdim + b) * Hdim + i) = v;
}

// ee[n][r] = Ee[t][b0+r][ibase + n*16]
template<int USEE>
__device__ __forceinline__ void load_ee8(const float* __restrict__ E,
                                         const float* __restrict__ beta,
                                         const int* __restrict__ x,
                                         int t, int b0, int ibase, float ee[2][4]) {
    if constexpr (USEE) {
        #pragma unroll
        for (int n = 0; n < 2; ++n)
            #pragma unroll
            for (int r = 0; r < 4; ++r)
                ee[n][r] = E[((size_t)t * Bdim + (b0 + r)) * Hdim + ibase + n * 16];
    } else {
        int xv[4];
        #pragma unroll
        for (int r = 0; r < 4; ++r) xv[r] = x[(b0 + r) * Tdim + t];
        #pragma unroll
        for (int n = 0; n < 2; ++n)
            #pragma unroll
            for (int r = 0; r < 4; ++r)
                ee[n][r] = __expf(beta[(size_t)(ibase + n * 16) * Vdim + xv[r]]);
    }
}

// Per-wave publish: 8 bf16 scatter stores + own vm0 drain + own flag (r7).
__device__ __forceinline__ void publish_vals(const float v[2][4],
                                             char* Yblk, char* flg_pw,
                                             int li, int np, int b0, unsigned seq) {
    #pragma unroll
    for (int r = 0; r < 4; ++r)
        #pragma unroll
        for (int u = 0; u < 2; ++u) {
            __bf16 h = (__bf16)v[u][r];
            unsigned hv = (unsigned)__builtin_bit_cast(unsigned short, h);
            st_b16_sc(Yblk + (b0 + r) * 128 + (np * 32 + u * 16 + li) * 2, hv);
        }
    WAITCNT_VM(0);
    if ((threadIdx.x & 63) == 0) st_b32_sc(flg_pw, seq);
}

template<int USEE>
__launch_bounds__(256, 1)
__global__ void k_hmm(const int* __restrict__ x,
                      const float* __restrict__ beta,
                      const float* __restrict__ gamma,
                      const __bf16* __restrict__ Abf,
                      char* __restrict__ Yb,        // [2][16][4096B]
                      char* __restrict__ flg,       // [2][64] x 64B
                      float* __restrict__ Psum,
                      float* __restrict__ Rbuf,
                      const float* __restrict__ Ebuf)
{
    extern __shared__ char smem[];
    char*  Vm    = smem;                        // [32][1024] bf16, swizzled
    float* Ltile = (float*)(smem + SM_LTILE);   // [4][32]
    float* Msh   = (float*)(smem + SM_MSH);     // [32] 1/M1

    const int p   = blockIdx.x;
    const int tid = threadIdx.x;
    const int w   = tid >> 6;
    const int l   = tid & 63;
    const int g   = l >> 4;
    const int li  = l & 15;
    const int mb  = w & 1;
    const int np  = w >> 1;
    const int b0  = mb * 16 + g * 4;
    const int i0  = p * 64 + np * 32 + li;      // slice output row (u=0)

    // ---- init: publish V0 = Ee[t=255] slice (raw), exchange 0 / parity 0 ----
    {
        float v0[2][4];
        load_ee8<USEE>(Ebuf, beta, x, Tdim - 1, b0, i0, v0);
        publish_vals(v0, Yb + p * 4096, flg + (size_t)(p * 4 + w) * 64,
                     li, np, b0, 1u);
    }

    float G = 0.f;   // per-b offset, valid in lanes tid<32

    for (int d = 0; d < NDSTEP; ++d) {
        const int t1    = 254 - 2 * d;
        const int t2    = t1 - 1;
        const int par_r = d & 1;
        const int par_w = (d + 1) & 1;

        // ---- poll 64 producer-wave flags (round-7 exact) ----
        {
            const char* fp = flg + (size_t)par_r * 4096 + l * 64;
            while (!__all((int)(ld_u32sync_sc(fp) >= (unsigned)(d + 1)))) {}
        }

        // ---- load full V (this wave: its 16 b-rows x all 1024 j) ----
        const char* yrow = Yb + (size_t)par_r * (NWG * 4096)
                         + (mb * 16 + li) * 128 + g * 16;
        u32x4 yreg[32];
        #pragma unroll
        for (int kc = 0; kc < 32; ++kc)
            yreg[kc] = ld_b128_sc(yrow + (kc >> 1) * 4096 + (kc & 1) * 64);
        WAITCNT_VM(0);

        // ---- FULL matvec: P1 = (A . V) * Ee_t1, chunked over 16 i-chunks ----
        float rm[4] = {0.f, 0.f, 0.f, 0.f};
        float eeC[2][4], eeN[2][4];
        load_ee8<USEE>(Ebuf, beta, x, t1, b0, np * 32 + li, eeC);
        #pragma unroll 1
        for (int c = 0; c < 16; ++c) {
            load_ee8<USEE>(Ebuf, beta, x, t1, b0,
                           ((c + 1) & 15) * 64 + np * 32 + li, eeN);
            f32x4 acc0 = {0.f, 0.f, 0.f, 0.f}, acc1 = {0.f, 0.f, 0.f, 0.f};
            const char* a0 = (const char*)Abf
                           + (size_t)(c * 64 + np * 32 + li) * 2048 + g * 16;
            const char* a1 = a0 + 16 * 2048;
            #pragma unroll
            for (int kc = 0; kc < 32; ++kc) {
                bf16x8 af0 = *(const bf16x8*)(a0 + kc * 64);
                bf16x8 af1 = *(const bf16x8*)(a1 + kc * 64);
                bf16x8 yf  = __builtin_bit_cast(bf16x8, yreg[kc]);
                acc0 = __builtin_amdgcn_mfma_f32_16x16x32_bf16(yf, af0, acc0, 0, 0, 0);
                acc1 = __builtin_amdgcn_mfma_f32_16x16x32_bf16(yf, af1, acc1, 0, 0, 0);
            }
            const int cbase = c * 64 + np * 32 + li;
            #pragma unroll
            for (int r = 0; r < 4; ++r) {
                float p0 = acc0[r] * eeC[0][r];
                float p1 = acc1[r] * eeC[1][r];
                float m = fmaxf(p0, p1);
                m = fmaxf(m, __shfl_xor(m, 1, 16));
                m = fmaxf(m, __shfl_xor(m, 2, 16));
                m = fmaxf(m, __shfl_xor(m, 4, 16));
                m = fmaxf(m, __shfl_xor(m, 8, 16));
                rm[r] = fmaxf(rm[r], m);
                const int b = b0 + r;
                const int sw = (b & 7) << 4;
                *(__bf16*)(Vm + ((b * 2048 + cbase * 2) ^ sw))        = (__bf16)p0;
                *(__bf16*)(Vm + ((b * 2048 + (cbase + 16) * 2) ^ sw)) = (__bf16)p1;
            }
            #pragma unroll
            for (int n = 0; n < 2; ++n)
                #pragma unroll
                for (int r = 0; r < 4; ++r) eeC[n][r] = eeN[n][r];
        }
        if (li == 0) {
            #pragma unroll
            for (int r = 0; r < 4; ++r) Ltile[w * 32 + b0 + r] = rm[r];
        }
        __syncthreads();
        if (tid < 32) {
            int m2 = tid >> 4;
            float M1 = fmaxf(Ltile[m2 * 32 + tid], Ltile[(m2 + 2) * 32 + tid]);
            G += __logf(M1);
            Msh[tid] = 1.0f / M1;
        }
        __syncthreads();

        // ---- SLICE matvec: P2 = (A_slice . Vmid) * Ee_t2, publish P2/M1 ----
        f32x4 acc0 = {0.f, 0.f, 0.f, 0.f}, acc1 = {0.f, 0.f, 0.f, 0.f};
        {
            const char* aS0 = (const char*)Abf + (size_t)i0 * 2048 + g * 16;
            const char* aS1 = aS0 + 16 * 2048;
            const int vrow = (mb * 16 + li) * 2048 + g * 16;
            const int vsw  = (li & 7) << 4;
            #pragma unroll
            for (int kc = 0; kc < 32; ++kc) {
                bf16x8 yf  = *(const bf16x8*)(Vm + ((vrow + kc * 64) ^ vsw));
                bf16x8 af0 = *(const bf16x8*)(aS0 + kc * 64);
                bf16x8 af1 = *(const bf16x8*)(aS1 + kc * 64);
                acc0 = __builtin_amdgcn_mfma_f32_16x16x32_bf16(yf, af0, acc0, 0, 0, 0);
                acc1 = __builtin_amdgcn_mfma_f32_16x16x32_bf16(yf, af1, acc1, 0, 0, 0);
            }
        }
        float ee2[2][4];
        load_ee8<USEE>(Ebuf, beta, x, t2, b0, i0, ee2);
        float vout[2][4];
        #pragma unroll
        for (int r = 0; r < 4; ++r) {
            float inv = Msh[b0 + r];
            vout[0][r] = acc0[r] * ee2[0][r] * inv;
            vout[1][r] = acc1[r] * ee2[1][r] * inv;
        }
        publish_vals(vout,
                     Yb + (size_t)par_w * (NWG * 4096) + p * 4096,
                     flg + (size_t)par_w * 4096 + (size_t)(p * 4 + w) * 64,
                     li, np, b0, (unsigned)(d + 2));
        __syncthreads();   // Vm reuse safety across dsteps
    }

    // ---- final single step (s=255, t=0): consume exchange 127 (parity 1) ----
    {
        const char* fp = flg + (size_t)4096 + l * 64;
        while (!__all((int)(ld_u32sync_sc(fp) >= (unsigned)(NDSTEP + 1)))) {}

        const char* yrow = Yb + (size_t)(NWG * 4096)
                         + (mb * 16 + li) * 128 + g * 16;
        u32x4 yreg[32];
        #pragma unroll
        for (int kc = 0; kc < 32; ++kc)
            yreg[kc] = ld_b128_sc(yrow + (kc >> 1) * 4096 + (kc & 1) * 64);
        WAITCNT_VM(0);

        f32x4 acc0 = {0.f, 0.f, 0.f, 0.f}, acc1 = {0.f, 0.f, 0.f, 0.f};
        const char* aS0 = (const char*)Abf + (size_t)i0 * 2048 + g * 16;
        const char* aS1 = aS0 + 16 * 2048;
        #pragma unroll
        for (int kc = 0; kc < 32; ++kc) {
            bf16x8 yf  = __builtin_bit_cast(bf16x8, yreg[kc]);
            bf16x8 af0 = *(const bf16x8*)(aS0 + kc * 64);
            bf16x8 af1 = *(const bf16x8*)(aS1 + kc * 64);
            acc0 = __builtin_amdgcn_mfma_f32_16x16x32_bf16(yf, af0, acc0, 0, 0, 0);
            acc1 = __builtin_amdgcn_mfma_f32_16x16x32_bf16(yf, af1, acc1, 0, 0, 0);
        }
        float ee0[2][4];
        load_ee8<USEE>(Ebuf, beta, x, 0, b0, i0, ee0);
        const float g0 = __expf(gamma[i0]);
        const float g1 = __expf(gamma[i0 + 16]);
        #pragma unroll
        for (int r = 0; r < 4; ++r) {
            float pa = g0 * acc0[r] * ee0[0][r] + g1 * acc1[r] * ee0[1][r];
            pa += __shfl_xor(pa, 1, 16);
            pa += __shfl_xor(pa, 2, 16);
            pa += __shfl_xor(pa, 4, 16);
            pa += __shfl_xor(pa, 8, 16);
            if (li == 0) atomicAdd(&Psum[b0 + r], pa);
        }
        if (p == 0 && tid < 32) Rbuf[tid] = G;
    }
}

__global__ void k_final(const float* __restrict__ Psum, const float* __restrict__ Rbuf,
                        float* __restrict__ out) {
    int b = threadIdx.x;
    if (b < 32) out[b] = Rbuf[b] + __logf(Psum[b]);
}

extern "C" void kernel_launch(void* const* d_in, const int* in_sizes, int n_in,
                              void* d_out, int out_size, void* d_ws, size_t ws_size,
                              hipStream_t stream) {
    const int*   x     = (const int*)d_in[0];
    const float* alpha = (const float*)d_in[1];
    const float* beta  = (const float*)d_in[2];
    const float* gamma = (const float*)d_in[3];

    char* ws = (char*)d_ws;
    __bf16* Abf  = (__bf16*)(ws + OFF_ABF);
    char*   Yb   = ws + OFF_YBUF;
    float*  Psum = (float*)(ws + OFF_PSUM);
    float*  Rbuf = (float*)(ws + OFF_RBUF);
    char*   flg  = ws + OFF_FLG;
    float*  Ebuf = (float*)(ws + OFF_E);

    int useE = (ws_size >= WS_E_NEED) ? 1 : 0;

    // zero Psum/Rbuf/flags every launch
    (void)hipMemsetAsync(ws + OFF_PSUM, 0, OFF_END0 - OFF_PSUM, stream);

    hipLaunchKernelGGL(k_expA, dim3((Hdim * Hdim) / (256 * 4)), dim3(256), 0, stream, alpha, Abf);

    if (useE) {
        hipLaunchKernelGGL(k_gather, dim3(Tdim * Bdim), dim3(256), 0, stream, x, beta, Ebuf);
        (void)hipFuncSetAttribute((const void*)k_hmm<1>, hipFuncAttributeMaxDynamicSharedMemorySize, SMEM_BYTES);
        hipLaunchKernelGGL(k_hmm<1>, dim3(NWG), dim3(256), SMEM_BYTES, stream,
                           x, beta, gamma, Abf, Yb, flg, Psum, Rbuf, Ebuf);
    } else {
        (void)hipFuncSetAttribute((const void*)k_hmm<0>, hipFuncAttributeMaxDynamicSharedMemorySize, SMEM_BYTES);
        hipLaunchKernelGGL(k_hmm<0>, dim3(NWG), dim3(256), SMEM_BYTES, stream,
                           x, beta, gamma, Abf, Yb, flg, Psum, Rbuf, (const float*)nullptr);
    }

    hipLaunchKernelGGL(k_final, dim3(1), dim3(64), 0, stream, Psum, Rbuf, (float*)d_out);
}

// Round 13
// 1965.611 us; speedup vs baseline: 8.8850x; 8.8850x over previous
//
#include <hip/hip_runtime.h>
#include <hip/hip_bf16.h>

// HMM backward recursion, B=32, T=256, H=1024, V=50257.
// y_s[b,i] = N_{s-1}[b] + log( sum_j expA[i,j] * Y_{s-1}[b,j] ) + e_t[b,i]
// Y_s = exp(y_s - N_s), N_s = max_i y_{s-1}[b,i] (one-step-stale upper bound).
// Round-7 proven substrate (16 persistent WGs, sc0sc1 exchange, per-wave
// flags, barrier-free step loop), with the beta-gather FUSED into the same
// kernel: blocks 16..8207 gather E[t][b][:] (high t first) via sc0sc1 stores
// and bump per-t ready counters; workers poll Eready[t] before each E
// prefetch until the grand counter says the gather is fully done.

#define Hdim 1024
#define Bdim 32
#define Tdim 256
#define Vdim 50257
#define NWG  16
#define SLICE 64
#define NGATHER (Tdim * Bdim)              // 8192

typedef __attribute__((ext_vector_type(8))) __bf16 bf16x8;
typedef __attribute__((ext_vector_type(4))) float  f32x4;
typedef __attribute__((ext_vector_type(4))) unsigned u32x4;

// workspace layout (bytes)
#define OFF_ABF   0                          // exp(alpha) bf16: 2 MB
#define OFF_YBUF  2097152                    // [2][16][4096B] = 131072
#define OFF_PSUM  (OFF_YBUF + 131072)        // 32 f32 (pad 128)
#define OFF_RBUF  (OFF_PSUM + 128)           // 32 f32 (pad 128)
#define OFF_WREC  (OFF_RBUF + 128)           // [2][16][4] x 64B = 8192
#define OFF_FLG   (OFF_WREC + 8192)          // [2][64] x 64B = 8192
#define OFF_ERDY  (OFF_FLG + 8192)           // 256 counters x 64B = 16384
#define OFF_GRD   (OFF_ERDY + 16384)         // grand counter (pad 128)
#define OFF_END0  (OFF_GRD + 128)
#define OFF_E     (((OFF_END0) + 4095) & ~4095)
#define WS_E_NEED ((size_t)OFF_E + (size_t)Tdim * Bdim * Hdim * 4)

// LDS carve
#define SM_A       131072                    // 64 rows x 1024 bf16 (swizzled)
#define SMEM_BYTES (SM_A + 256)

// ---- sc0 sc1 (device-scope, cache-bypass) access helpers ----
__device__ __forceinline__ void st_b16_sc(void* p, unsigned v) {
    asm volatile("global_store_short %0, %1, off sc0 sc1" :: "v"(p), "v"(v) : "memory");
}
__device__ __forceinline__ void st_b32_sc(void* p, unsigned v) {
    asm volatile("global_store_dword %0, %1, off sc0 sc1" :: "v"(p), "v"(v) : "memory");
}
__device__ __forceinline__ void st_b128_sc(void* p, u32x4 v) {
    asm volatile("global_store_dwordx4 %0, %1, off sc0 sc1" :: "v"(p), "v"(v) : "memory");
}
__device__ __forceinline__ u32x4 ld_b128_sc(const void* p) {
    u32x4 r;
    asm volatile("global_load_dwordx4 %0, %1, off sc0 sc1" : "=v"(r) : "v"(p) : "memory");
    return r;
}
__device__ __forceinline__ float ld_f32_sc(const void* p) {
    float r;
    asm volatile("global_load_dword %0, %1, off sc0 sc1" : "=v"(r) : "v"(p) : "memory");
    return r;
}
__device__ __forceinline__ unsigned ld_u32sync_sc(const void* p) {
    unsigned r;
    asm volatile("global_load_dword %0, %1, off sc0 sc1\n\ts_waitcnt vmcnt(0)"
                 : "=v"(r) : "v"(p) : "memory");
    return r;
}
__device__ __forceinline__ void waitcnt_vm0() {
    asm volatile("s_waitcnt vmcnt(0)" ::: "memory");
    __builtin_amdgcn_sched_barrier(0);
}
__device__ __forceinline__ void waitcnt_vm32() {
    asm volatile("s_waitcnt vmcnt(32)" ::: "memory");
    __builtin_amdgcn_sched_barrier(0);
}

__global__ void k_expA(const float* __restrict__ alpha, __bf16* __restrict__ Abf) {
    int idx = (blockIdx.x * 256 + threadIdx.x) * 4;
    float4 v = *(const float4*)(alpha + idx);
    union { __bf16 h[4]; uint2 u; } cv;
    cv.h[0] = (__bf16)__expf(v.x);
    cv.h[1] = (__bf16)__expf(v.y);
    cv.h[2] = (__bf16)__expf(v.z);
    cv.h[3] = (__bf16)__expf(v.w);
    *(uint2*)(Abf + idx) = cv.u;
}

// compiler-load e (init + no-E fallback)
__device__ __forceinline__ void load_e(const float* __restrict__ E,
                                       const float* __restrict__ beta,
                                       const int* __restrict__ x,
                                       int t, int b0, int i0, int useE, float e[2][4]) {
    if (useE) {
        #pragma unroll
        for (int u = 0; u < 2; ++u)
            #pragma unroll
            for (int r = 0; r < 4; ++r)
                e[u][r] = E[((size_t)t * Bdim + (b0 + r)) * Hdim + i0 + u * 16];
    } else {
        int xv[4];
        #pragma unroll
        for (int r = 0; r < 4; ++r) xv[r] = x[(b0 + r) * Tdim + t];
        #pragma unroll
        for (int u = 0; u < 2; ++u)
            #pragma unroll
            for (int r = 0; r < 4; ++r)
                e[u][r] = beta[(size_t)(i0 + u * 16) * Vdim + xv[r]];
    }
}

// Per-WAVE publish (round-7 exact): Y direct from regs (8 b16 stores/lane),
// per-b maxes as one b128 (li==0), own vm0 drain, own flag. No barrier.
__device__ __forceinline__ void publish_wave(const float y[2][4], const float Gc[4],
                                             char* Yblk,     // Ybuf[par] + p*4096
                                             char* wrec_pw,  // wrec[par][p][w]
                                             char* flg_pw,   // flg[par][p*4+w]
                                             int li, int g, int np, int b0,
                                             unsigned seq) {
    float mx[4];
    #pragma unroll
    for (int r = 0; r < 4; ++r) {
        #pragma unroll
        for (int u = 0; u < 2; ++u) {
            float Yn = __expf(y[u][r] - Gc[r]);
            __bf16 h = (__bf16)Yn;
            unsigned hv = (unsigned)__builtin_bit_cast(unsigned short, h);
            st_b16_sc(Yblk + (b0 + r) * 128 + (np * 32 + u * 16 + li) * 2, hv);
        }
        float m = fmaxf(y[0][r], y[1][r]);
        m = fmaxf(m, __shfl_xor(m, 1, 16));
        m = fmaxf(m, __shfl_xor(m, 2, 16));
        m = fmaxf(m, __shfl_xor(m, 4, 16));
        m = fmaxf(m, __shfl_xor(m, 8, 16));
        mx[r] = m;
    }
    if (li == 0) {
        f32x4 mv = {mx[0], mx[1], mx[2], mx[3]};
        st_b128_sc(wrec_pw + g * 16, __builtin_bit_cast(u32x4, mv));
    }
    asm volatile("s_waitcnt vmcnt(0)" ::: "memory");
    if ((threadIdx.x & 63) == 0) st_b32_sc(flg_pw, seq);
}

// Worker-side E readiness gate: no-op once grand counter hit NGATHER.
__device__ __forceinline__ void poll_eready(const char* erdy, const char* grd,
                                            int t, int* edone) {
    if (*edone) return;
    if (ld_u32sync_sc(grd) >= (unsigned)NGATHER) { *edone = 1; return; }
    const char* ep = erdy + (size_t)t * 64;
    while (ld_u32sync_sc(ep) < (unsigned)Bdim) {}
}

template<int USEE>
__launch_bounds__(256, 1)
__global__ void k_hmm(const int* __restrict__ x,
                      const float* __restrict__ beta,
                      const float* __restrict__ gamma,
                      const __bf16* __restrict__ Abf,
                      char* __restrict__ Yb,        // [2][16][4096B]
                      char* __restrict__ wrec,      // [2][16][4] x 64B
                      char* __restrict__ flg,       // [2][64] x 64B
                      char* __restrict__ erdy,      // 256 x 64B
                      char* __restrict__ grd,       // grand counter
                      float* __restrict__ Psum,
                      float* __restrict__ Rbuf,
                      float* __restrict__ Ebuf)
{
    // ---------------- gather role (blocks >= NWG) ----------------
    if (USEE && blockIdx.x >= NWG) {
        const int idx = blockIdx.x - NWG;
        const int t   = (Tdim - 1) - (idx >> 5);   // high t first
        const int b   = idx & 31;
        const int xv  = x[b * Tdim + t];
        const int i   = threadIdx.x * 4;
        f32x4 v;
        v[0] = beta[(size_t)(i + 0) * Vdim + xv];
        v[1] = beta[(size_t)(i + 1) * Vdim + xv];
        v[2] = beta[(size_t)(i + 2) * Vdim + xv];
        v[3] = beta[(size_t)(i + 3) * Vdim + xv];
        st_b128_sc(Ebuf + ((size_t)t * Bdim + b) * Hdim + i,
                   __builtin_bit_cast(u32x4, v));
        waitcnt_vm0();
        __syncthreads();
        if (threadIdx.x == 0) {
            atomicAdd((unsigned*)(erdy + (size_t)t * 64), 1u);
            atomicAdd((unsigned*)grd, 1u);
        }
        return;
    }

    // ---------------- worker role (round-7 exact core) ----------------
    extern __shared__ char smem[];
    char* Asl = smem;

    const int p   = blockIdx.x;
    const int tid = threadIdx.x;
    const int w   = tid >> 6;
    const int l   = tid & 63;
    const int g   = l >> 4;
    const int li  = l & 15;
    const int mb  = w & 1;
    const int np  = w >> 1;
    const int b0  = mb * 16 + g * 4;
    const int i0  = p * SLICE + np * 32 + li;

    int edone = USEE ? 0 : 1;

    // ---- stage A slice into LDS, XOR-swizzled for b128 reads ----
    #pragma unroll
    for (int rep = 0; rep < 32; ++rep) {
        int flat = rep * 256 + tid;
        int row  = flat >> 7;
        int c16  = flat & 127;
        uint4 v = *(const uint4*)((const char*)Abf + (size_t)(p * 64 + row) * 2048 + c16 * 16);
        int off = (row * 2048 + c16 * 16) ^ ((row & 7) << 4);
        *(uint4*)(Asl + off) = v;
    }
    __syncthreads();    // only barrier in the worker (A staging)

    // ---- init: y0 = e[:, T-1], publish per-wave ----
    poll_eready(erdy, grd, Tdim - 1, &edone);
    poll_eready(erdy, grd, Tdim - 2, &edone);
    {
        float y0[2][4];
        load_e(Ebuf, beta, x, Tdim - 1, b0, i0, USEE, y0);
        float Gc0[4] = {0.f, 0.f, 0.f, 0.f};
        publish_wave(y0, Gc0, Yb + p * 4096,
                     wrec + (size_t)p * 256 + w * 64,
                     flg + (size_t)(p * 4 + w) * 64,
                     li, g, np, b0, 1u);
    }

    float Nprev[4] = {0.f, 0.f, 0.f, 0.f};
    float ereg[2][4];
    load_e(Ebuf, beta, x, Tdim - 2, b0, i0, USEE, ereg);

    for (int s = 1; s < Tdim; ++s) {
        const int t     = Tdim - 1 - s;
        const int par_r = (s - 1) & 1;
        const int par_w = s & 1;

        // prefetch next step's e (gate on gather readiness while needed);
        // drain BEFORE polling flags so the detect loop never waits on it
        float eregN[2][4];
        if (s < Tdim - 1) {
            poll_eready(erdy, grd, t - 1, &edone);
            load_e(Ebuf, beta, x, t - 1, b0, i0, USEE, eregN);
        }
        float gl[2] = {0.f, 0.f};
        if (s == Tdim - 1) { gl[0] = gamma[i0]; gl[1] = gamma[i0 + 16]; }
        waitcnt_vm0();

        // ---- poll all 64 producer-wave flags (each wave independently) ----
        {
            const char* fp = flg + (size_t)par_r * 4096 + l * 64;
            while (!__all((int)(ld_u32sync_sc(fp) >= (unsigned)s))) {}
        }

        // ---- issue Y loads (32 b128), then wrec loads (32 f32, lanes<32) ----
        const char* Ybase = Yb + (size_t)par_r * (NWG * 4096);
        const char* yrow  = Ybase + (mb * 16 + li) * 128 + g * 16;
        u32x4 yreg[32];
        #pragma unroll
        for (int kc = 0; kc < 32; ++kc)
            yreg[kc] = ld_b128_sc(yrow + (kc >> 1) * 4096 + (kc & 1) * 64);

        float gmv[32];
        {
            const char* wbase = wrec + (size_t)par_r * 4096;
            if (l < 32) {
                int bmb = l >> 4;          // 16-block of b
                int idx = (l & 15) * 4;
                #pragma unroll
                for (int q = 0; q < 16; ++q) {
                    gmv[2 * q]     = ld_f32_sc(wbase + q * 256 + bmb * 64 + idx);
                    gmv[2 * q + 1] = ld_f32_sc(wbase + q * 256 + (bmb + 2) * 64 + idx);
                }
            }
        }

        waitcnt_vm32();   // Y loads (oldest 32) done; wrec still in flight

        // ---- S[b, i-slice] = sum_j expA[i,j] * Y[b,j] ----
        f32x4 acc0 = {0.f, 0.f, 0.f, 0.f}, acc1 = {0.f, 0.f, 0.f, 0.f};
        {
            const int ia = np * 32 + li;
            const int ib = ia + 16;
            const int basea = ia * 2048 + g * 16, xa = (ia & 7) << 4;
            const int baseb = ib * 2048 + g * 16, xb = (ib & 7) << 4;
            #pragma unroll
            for (int kc = 0; kc < 32; ++kc) {
                bf16x8 af0 = *(const bf16x8*)(Asl + ((basea + kc * 64) ^ xa));
                bf16x8 af1 = *(const bf16x8*)(Asl + ((baseb + kc * 64) ^ xb));
                bf16x8 yf  = __builtin_bit_cast(bf16x8, yreg[kc]);
                acc0 = __builtin_amdgcn_mfma_f32_16x16x32_bf16(yf, af0, acc0, 0, 0, 0);
                acc1 = __builtin_amdgcn_mfma_f32_16x16x32_bf16(yf, af1, acc1, 0, 0, 0);
            }
        }

        waitcnt_vm0();    // wrec loads done

        // per-b global max in registers + wave-local broadcast (no LDS)
        float gm = -3.0e38f;
        if (l < 32) {
            #pragma unroll
            for (int q = 0; q < 32; ++q) gm = fmaxf(gm, gmv[q]);
        }
        float Gcur[4];
        #pragma unroll
        for (int r = 0; r < 4; ++r) Gcur[r] = __shfl(gm, b0 + r);

        float yv[2][4];
        #pragma unroll
        for (int r = 0; r < 4; ++r) {
            yv[0][r] = Nprev[r] + __logf(acc0[r]) + ereg[0][r];
            yv[1][r] = Nprev[r] + __logf(acc1[r]) + ereg[1][r];
        }

        if (s < Tdim - 1) {
            publish_wave(yv, Gcur,
                         Yb + (size_t)par_w * (NWG * 4096) + p * 4096,
                         wrec + (size_t)par_w * 4096 + (size_t)p * 256 + w * 64,
                         flg + (size_t)par_w * 4096 + (size_t)(p * 4 + w) * 64,
                         li, g, np, b0, (unsigned)(s + 1));
            #pragma unroll
            for (int r = 0; r < 4; ++r) Nprev[r] = Gcur[r];
            #pragma unroll
            for (int u = 0; u < 2; ++u)
                #pragma unroll
                for (int r = 0; r < 4; ++r) ereg[u][r] = eregN[u][r];
        } else {
            #pragma unroll
            for (int r = 0; r < 4; ++r) {
                float pa = __expf(gl[0] + yv[0][r] - Gcur[r])
                         + __expf(gl[1] + yv[1][r] - Gcur[r]);
                pa += __shfl_xor(pa, 1, 16);
                pa += __shfl_xor(pa, 2, 16);
                pa += __shfl_xor(pa, 4, 16);
                pa += __shfl_xor(pa, 8, 16);
                if (li == 0) {
                    atomicAdd(&Psum[b0 + r], pa);
                    if (p == 0) Rbuf[b0 + r] = Gcur[r];
                }
            }
        }
    }
}

__global__ void k_final(const float* __restrict__ Psum, const float* __restrict__ Rbuf,
                        float* __restrict__ out) {
    int b = threadIdx.x;
    if (b < 32) out[b] = Rbuf[b] + __logf(Psum[b]);
}

extern "C" void kernel_launch(void* const* d_in, const int* in_sizes, int n_in,
                              void* d_out, int out_size, void* d_ws, size_t ws_size,
                              hipStream_t stream) {
    const int*   x     = (const int*)d_in[0];
    const float* alpha = (const float*)d_in[1];
    const float* beta  = (const float*)d_in[2];
    const float* gamma = (const float*)d_in[3];

    char* ws = (char*)d_ws;
    __bf16* Abf  = (__bf16*)(ws + OFF_ABF);
    char*   Yb   = ws + OFF_YBUF;
    float*  Psum = (float*)(ws + OFF_PSUM);
    float*  Rbuf = (float*)(ws + OFF_RBUF);
    char*   wrec = ws + OFF_WREC;
    char*   flg  = ws + OFF_FLG;
    char*   erdy = ws + OFF_ERDY;
    char*   grd  = ws + OFF_GRD;
    float*  Ebuf = (float*)(ws + OFF_E);

    int useE = (ws_size >= WS_E_NEED) ? 1 : 0;

    // zero Psum/Rbuf/wrec/flags/Eready/grand every launch
    (void)hipMemsetAsync(ws + OFF_PSUM, 0, OFF_END0 - OFF_PSUM, stream);

    hipLaunchKernelGGL(k_expA, dim3((Hdim * Hdim) / (256 * 4)), dim3(256), 0, stream, alpha, Abf);

    if (useE) {
        (void)hipFuncSetAttribute((const void*)k_hmm<1>, hipFuncAttributeMaxDynamicSharedMemorySize, SMEM_BYTES);
        hipLaunchKernelGGL(k_hmm<1>, dim3(NWG + NGATHER), dim3(256), SMEM_BYTES, stream,
                           x, beta, gamma, Abf, Yb, wrec, flg, erdy, grd, Psum, Rbuf, Ebuf);
    } else {
        (void)hipFuncSetAttribute((const void*)k_hmm<0>, hipFuncAttributeMaxDynamicSharedMemorySize, SMEM_BYTES);
        hipLaunchKernelGGL(k_hmm<0>, dim3(NWG), dim3(256), SMEM_BYTES, stream,
                           x, beta, gamma, Abf, Yb, wrec, flg, erdy, grd, Psum, Rbuf, (float*)nullptr);
    }

    hipLaunchKernelGGL(k_final, dim3(1), dim3(64), 0, stream, Psum, Rbuf, (float*)d_out);
}